// Round 1
// baseline (19113.440 us; speedup 1.0000x reference)
//
#include <hip/hip_runtime.h>
#include <hip/hip_bf16.h>
#include <stdint.h>

// ============================================================================
// ReservoirBlock (ESN) on MI355X -- Round 1 (correctness-first full pipeline)
//
// Pipeline: zero_ctr | prep_x (x->XT f16 [T][B][D]) | prep_w (Wr1,Wr2 -> f16)
//        -> reservoir_kernel: 16 WGs (2 reservoirs x 8 chunks of 64 cols),
//           W shards live in VGPRs as MFMA A-frags; per-step cross-WG sync via
//           device-scope atomics (XCD-agnostic, fresh flag/data lines per t).
//        -> gemm_h (S@Wr1^T + br1, LeakyReLU -> H f16)
//        -> gemm_o (H@Wr2^T + br2 -> out fp32, row (t,b) -> out[b][t][:]).
//
// MFMA 16x16x32 f16 layout assumptions (to verify vs validation):
//   A-frag: lane l holds A[l&15][(l>>4)*8 + e], e=0..7 (8 consecutive k)
//   B-frag: lane l holds B[(l>>4)*8 + e][l&15]
//   C/D:    col = lane&15, row = (lane>>4)*4 + reg   (m89/m91-verified)
// Recurrence uses "swapped" form: D[n][b] = sum_k W[n][k] * s[b][k]
//   => A = W rows (static, in regs), B = state cols (loaded per step),
//      D row = n (4 consecutive per lane -> single 8B store), D col = b.
// ============================================================================

#define TT 2048
#define BB 16
#define DD 256
#define NR 512
#define HH 1024
#define EE 256

typedef _Float16 half8 __attribute__((ext_vector_type(8)));
typedef _Float16 half4 __attribute__((ext_vector_type(4)));
typedef float floatx4 __attribute__((ext_vector_type(4)));
typedef int intx4 __attribute__((ext_vector_type(4)));

#define MFMA(A, B, C) __builtin_amdgcn_mfma_f32_16x16x32_f16((A), (B), (C), 0, 0, 0)

// workspace layout (bytes)
#define OFF_XT   0ull                       // [2048][16][256] f16  = 16 MB
#define OFF_S    16777216ull                // [2048][16][1024] f16 = 64 MB
#define OFF_H    83886080ull                // [32768][1024] f16    = 64 MB
#define OFF_W1F  150994944ull               // [1024][1024] f16     = 2 MB
#define OFF_W2F  153092096ull               // [256][1024] f16      = 0.5 MB
#define OFF_CTR  153616384ull               // [2048][2] u32        = 16 KB

__device__ __forceinline__ float tanh_fast(float x) {
    // 1 - 2/(exp(2x)+1); exp overflow -> inf -> 1, underflow -> 0 -> -1. OK.
    float e = __expf(2.0f * x);
    return 1.0f - 2.0f / (e + 1.0f);
}

__global__ void zero_ctr_kernel(unsigned int* __restrict__ c) {
    c[blockIdx.x * 256 + threadIdx.x] = 0u;   // grid 16 x 256 = 4096 = [2048][2]
}

__global__ void prep_x_kernel(const float* __restrict__ x, _Float16* __restrict__ XT) {
    // x[b][t][d] fp32 -> XT[t][b][d] f16 ; 8 elems/thread; grid 4096x256 exact
    int idx = blockIdx.x * 256 + threadIdx.x;
    int dblk = idx & 31;
    int tmp = idx >> 5;
    int t = tmp & (TT - 1);
    int b = tmp >> 11;
    const float* src = x + ((size_t)b * TT + t) * DD + dblk * 8;
    floatx4 f0 = *(const floatx4*)src;
    floatx4 f1 = *(const floatx4*)(src + 4);
    half8 h;
#pragma unroll
    for (int e = 0; e < 4; ++e) { h[e] = (_Float16)f0[e]; h[4 + e] = (_Float16)f1[e]; }
    *(half8*)(XT + ((size_t)t * BB + b) * DD + dblk * 8) = h;
}

__global__ void prep_w_kernel(const float* __restrict__ src, _Float16* __restrict__ dst) {
    int idx = blockIdx.x * 256 + threadIdx.x;   // 8 elems/thread, exact grid
    const float* s = src + (size_t)idx * 8;
    floatx4 f0 = *(const floatx4*)s;
    floatx4 f1 = *(const floatx4*)(s + 4);
    half8 h;
#pragma unroll
    for (int e = 0; e < 4; ++e) { h[e] = (_Float16)f0[e]; h[4 + e] = (_Float16)f1[e]; }
    *(half8*)(dst + (size_t)idx * 8) = h;
}

__global__ __launch_bounds__(256, 1) void reservoir_kernel(
    const float* __restrict__ W0, const float* __restrict__ Win0,
    const float* __restrict__ W1, const float* __restrict__ Win1,
    const _Float16* __restrict__ XT, _Float16* __restrict__ S,
    unsigned int* __restrict__ CTR)
{
    const int wg = blockIdx.x;          // 0..15
    const int rsv = wg >> 3;            // reservoir 0/1
    const int chunk = wg & 7;           // 0..7 (64 cols each)
    const int wave = threadIdx.x >> 6;  // 0..3 (16 cols each)
    const int lane = threadIdx.x & 63;
    const int r15 = lane & 15;
    const int kg = (lane >> 4) << 3;    // 0,8,16,24
    const int nb = chunk * 64 + wave * 16;

    const float* Wm = rsv ? W1 : W0;
    const float* Wi = rsv ? Win1 : Win0;

    // --- load static weight A-frags into registers (f16) ---
    half8 wfrag[16];
#pragma unroll
    for (int ks = 0; ks < 16; ++ks) {
        const float* p = Wm + (size_t)(nb + r15) * NR + ks * 32 + kg;
        floatx4 f0 = *(const floatx4*)p;
        floatx4 f1 = *(const floatx4*)(p + 4);
        half8 f;
#pragma unroll
        for (int e = 0; e < 4; ++e) { f[e] = (_Float16)f0[e]; f[4 + e] = (_Float16)f1[e]; }
        wfrag[ks] = f;
    }
    half8 ifrag[8];
#pragma unroll
    for (int ks = 0; ks < 8; ++ks) {
        const float* p = Wi + (size_t)(nb + r15) * DD + ks * 32 + kg;
        floatx4 f0 = *(const floatx4*)p;
        floatx4 f1 = *(const floatx4*)(p + 4);
        half8 f;
#pragma unroll
        for (int e = 0; e < 4; ++e) { f[e] = (_Float16)f0[e]; f[4 + e] = (_Float16)f1[e]; }
        ifrag[ks] = f;
    }

    floatx4 sprev = {0.f, 0.f, 0.f, 0.f};
    const int nstore = nb + ((lane >> 4) << 2);  // D rows: 4 consecutive n per lane

    for (int t = 0; t < TT; ++t) {
        // prefetch input frags (independent of state -> issue early)
        const _Float16* xr = XT + ((size_t)t * BB + r15) * DD + kg;
        intx4 xi[8];
#pragma unroll
        for (int ks = 0; ks < 8; ++ks) xi[ks] = *(const intx4*)(xr + ks * 32);

        floatx4 acc[4];
#pragma unroll
        for (int j = 0; j < 4; ++j) acc[j] = (floatx4){0.f, 0.f, 0.f, 0.f};

        if (t > 0) {
            // wait for all 32 waves of this reservoir to publish step t-1
            const unsigned int* cp = CTR + (size_t)(t - 1) * 2 + rsv;
            while (__hip_atomic_load(cp, __ATOMIC_RELAXED, __HIP_MEMORY_SCOPE_AGENT) < 32u) {}
            (void)__hip_atomic_load(cp, __ATOMIC_ACQUIRE, __HIP_MEMORY_SCOPE_AGENT);
            asm volatile("" ::: "memory");
            // state B-frags: fresh lines every step -> plain loads are safe
            const _Float16* sr = S + ((size_t)(t - 1) * BB + r15) * (2 * NR) + rsv * NR + kg;
#pragma unroll
            for (int ks = 0; ks < 16; ++ks) {
                intx4 si = *(const intx4*)(sr + ks * 32);
                half8 sf = __builtin_bit_cast(half8, si);
                acc[ks & 3] = MFMA(wfrag[ks], sf, acc[ks & 3]);
            }
        }
#pragma unroll
        for (int ks = 0; ks < 8; ++ks) {
            half8 xf = __builtin_bit_cast(half8, xi[ks]);
            acc[ks & 3] = MFMA(ifrag[ks], xf, acc[ks & 3]);
        }

        floatx4 z = acc[0] + acc[1] + acc[2] + acc[3];
        floatx4 sn;
#pragma unroll
        for (int q = 0; q < 4; ++q)
            sn[q] = 0.7f * sprev[q] + 0.3f * tanh_fast(z[q]);
        sprev = sn;

        union { half4 h; unsigned long long u; } pk;
#pragma unroll
        for (int q = 0; q < 4; ++q) pk.h[q] = (_Float16)sn[q];
        unsigned long long* sp = (unsigned long long*)
            (S + ((size_t)t * BB + r15) * (2 * NR) + rsv * NR + nstore);
        // device-scope store: visible at coherence point (XCD-agnostic)
        __hip_atomic_store(sp, pk.u, __ATOMIC_RELAXED, __HIP_MEMORY_SCOPE_AGENT);
        if (lane == 0) {
            // RELEASE orders all prior stores before the counter bump
            (void)__hip_atomic_fetch_add(CTR + (size_t)t * 2 + rsv, 1u,
                                         __ATOMIC_RELEASE, __HIP_MEMORY_SCOPE_AGENT);
        }
    }
}

__global__ __launch_bounds__(256) void gemm_h_kernel(
    const _Float16* __restrict__ S, const _Float16* __restrict__ W1F,
    const float* __restrict__ br1, _Float16* __restrict__ H)
{
    const int wave = threadIdx.x >> 6, lane = threadIdx.x & 63;
    const int r15 = lane & 15, kg = (lane >> 4) << 3;
    const int m0 = blockIdx.x * 64 + wave * 16;
    const int n0 = blockIdx.y * 64;
    const _Float16* ap = S + (size_t)(m0 + r15) * HH + kg;
    const _Float16* bp = W1F + (size_t)(n0 + r15) * HH + kg;
    floatx4 acc[4];
#pragma unroll
    for (int j = 0; j < 4; ++j) acc[j] = (floatx4){0.f, 0.f, 0.f, 0.f};
    for (int ks = 0; ks < HH / 32; ++ks) {
        half8 af = __builtin_bit_cast(half8, *(const intx4*)(ap + ks * 32));
#pragma unroll
        for (int j = 0; j < 4; ++j) {
            half8 bf = __builtin_bit_cast(half8, *(const intx4*)(bp + (size_t)j * 16 * HH + ks * 32));
            acc[j] = MFMA(af, bf, acc[j]);
        }
    }
    const int mr = m0 + ((lane >> 4) << 2);
#pragma unroll
    for (int j = 0; j < 4; ++j) {
        int n = n0 + j * 16 + r15;
        float bb = br1[n];
#pragma unroll
        for (int q = 0; q < 4; ++q) {
            float h = acc[j][q] + bb;
            h = (h >= 0.f) ? h : 0.01f * h;
            H[(size_t)(mr + q) * HH + n] = (_Float16)h;
        }
    }
}

__global__ __launch_bounds__(256) void gemm_o_kernel(
    const _Float16* __restrict__ H, const _Float16* __restrict__ W2F,
    const float* __restrict__ br2, float* __restrict__ OUT)
{
    const int wave = threadIdx.x >> 6, lane = threadIdx.x & 63;
    const int r15 = lane & 15, kg = (lane >> 4) << 3;
    const int m0 = blockIdx.x * 64 + wave * 16;
    const int n0 = blockIdx.y * 64;
    const _Float16* ap = H + (size_t)(m0 + r15) * HH + kg;
    const _Float16* bp = W2F + (size_t)(n0 + r15) * HH + kg;
    floatx4 acc[4];
#pragma unroll
    for (int j = 0; j < 4; ++j) acc[j] = (floatx4){0.f, 0.f, 0.f, 0.f};
    for (int ks = 0; ks < HH / 32; ++ks) {
        half8 af = __builtin_bit_cast(half8, *(const intx4*)(ap + ks * 32));
#pragma unroll
        for (int j = 0; j < 4; ++j) {
            half8 bf = __builtin_bit_cast(half8, *(const intx4*)(bp + (size_t)j * 16 * HH + ks * 32));
            acc[j] = MFMA(af, bf, acc[j]);
        }
    }
    const int mr = m0 + ((lane >> 4) << 2);
#pragma unroll
    for (int j = 0; j < 4; ++j) {
        int n = n0 + j * 16 + r15;
        float bb = br2[n];
#pragma unroll
        for (int q = 0; q < 4; ++q) {
            int m = mr + q;           // m = t*16 + b
            int b = m & 15;
            int tt = m >> 4;
            OUT[(size_t)b * TT * EE + (size_t)tt * EE + n] = acc[j][q] + bb;
        }
    }
}

extern "C" void kernel_launch(void* const* d_in, const int* in_sizes, int n_in,
                              void* d_out, int out_size, void* d_ws, size_t ws_size,
                              hipStream_t stream) {
    const float* x    = (const float*)d_in[0];
    const float* W0   = (const float*)d_in[1];
    const float* Win0 = (const float*)d_in[2];
    const float* W1   = (const float*)d_in[3];
    const float* Win1 = (const float*)d_in[4];
    const float* Wr1  = (const float*)d_in[5];
    const float* br1  = (const float*)d_in[6];
    const float* Wr2  = (const float*)d_in[7];
    const float* br2  = (const float*)d_in[8];
    float* out = (float*)d_out;

    char* ws = (char*)d_ws;
    _Float16* XT  = (_Float16*)(ws + OFF_XT);
    _Float16* S   = (_Float16*)(ws + OFF_S);
    _Float16* H   = (_Float16*)(ws + OFF_H);
    _Float16* W1F = (_Float16*)(ws + OFF_W1F);
    _Float16* W2F = (_Float16*)(ws + OFF_W2F);
    unsigned int* C = (unsigned int*)(ws + OFF_CTR);

    zero_ctr_kernel<<<16, 256, 0, stream>>>(C);
    prep_x_kernel<<<4096, 256, 0, stream>>>(x, XT);
    prep_w_kernel<<<512, 256, 0, stream>>>(Wr1, W1F);   // 1024*1024/8/256
    prep_w_kernel<<<128, 256, 0, stream>>>(Wr2, W2F);   // 256*1024/8/256
    reservoir_kernel<<<16, 256, 0, stream>>>(W0, Win0, W1, Win1, XT, S, C);
    gemm_h_kernel<<<dim3(512, 16), 256, 0, stream>>>(S, W1F, br1, H);
    gemm_o_kernel<<<dim3(512, 4), 256, 0, stream>>>(H, W2F, br2, out);
}

// Round 2
// 13580.211 us; speedup vs baseline: 1.4074x; 1.4074x over previous
//
#include <hip/hip_runtime.h>
#include <hip/hip_bf16.h>
#include <stdint.h>

// ============================================================================
// ReservoirBlock (ESN) on MI355X -- Round 2
//
// Change vs R1: reservoir sync rebuilt. No acquire/release bulk cache ops,
// no RMW counters. Cross-WG lines (state S, flags) use per-instruction
// coherent ops (sc0 sc1 = bypass L1+L2, L3 is the XCD-agnostic coherence
// point). 2 reservoirs x 4 WGs x 512 thr (8 waves, 16 cols/wave, W f16 in
// VGPRs: 64 VGPR wfrag + 32 ifrag). Producer: sc1 stores -> vmcnt(0) ->
// barrier -> lane0 flag=t+1. Consumer: one dwordx4 coherent poll of all 4
// flags, then 16 coherent dwordx4 state loads in one asm block.
//
// MFMA 16x16x32 f16 layouts (validated by R1 pass):
//   A-frag: lane l holds A[l&15][(l>>4)*8+e]      (W rows)
//   B-frag: lane l holds B[(l>>4)*8+e][l&15]      (state col b=l&15)
//   C/D:    col(b) = lane&15, row(n) = (lane>>4)*4+reg
// ============================================================================

#define TT 2048
#define BB 16
#define DD 256
#define NR 512
#define HH 1024
#define EE 256

typedef _Float16 half8 __attribute__((ext_vector_type(8)));
typedef _Float16 half4 __attribute__((ext_vector_type(4)));
typedef float floatx4 __attribute__((ext_vector_type(4)));
typedef int intx4 __attribute__((ext_vector_type(4)));

#define MFMA(A, B, C) __builtin_amdgcn_mfma_f32_16x16x32_f16((A), (B), (C), 0, 0, 0)

// workspace layout (bytes)  -- total ~147.1 MB (R1 used 153.6 MB, fits)
#define OFF_XT   0ull                      // [2048][16][256] f16        = 16 MB
#define OFF_S    16777216ull               // [2048][2][16][512] f16     = 64 MB
#define OFF_H    83886080ull               // [32768][1024] f16          = 64 MB
#define OFF_W1F  150994944ull              // [1024][1024] f16           = 2 MB
#define OFF_W2F  153092096ull              // [256][1024] f16            = 0.5 MB
#define OFF_FLG  153616384ull              // [2048][2][4] u32           = 64 KB

__device__ __forceinline__ float tanh_fast(float x) {
    float e = __expf(2.0f * x);
    return 1.0f - 2.0f / (e + 1.0f);
}

// S element index: [t][rsv][b][k], k in [0,512)
__device__ __forceinline__ size_t sidx(int t, int rsv, int b, int k) {
    return ((((size_t)t * 2 + rsv) * BB + b) << 9) + k;
}

__global__ void zero_flags_kernel(unsigned int* __restrict__ f) {
    f[blockIdx.x * 256 + threadIdx.x] = 0u;   // 64 x 256 = 16384 = [2048][2][4]
}

__global__ void prep_x_kernel(const float* __restrict__ x, _Float16* __restrict__ XT) {
    // x[b][t][d] fp32 -> XT[t][b][d] f16 ; 8 elems/thread
    int idx = blockIdx.x * 256 + threadIdx.x;
    int dblk = idx & 31;
    int tmp = idx >> 5;
    int t = tmp & (TT - 1);
    int b = tmp >> 11;
    const float* src = x + ((size_t)b * TT + t) * DD + dblk * 8;
    floatx4 f0 = *(const floatx4*)src;
    floatx4 f1 = *(const floatx4*)(src + 4);
    half8 h;
#pragma unroll
    for (int e = 0; e < 4; ++e) { h[e] = (_Float16)f0[e]; h[4 + e] = (_Float16)f1[e]; }
    *(half8*)(XT + ((size_t)t * BB + b) * DD + dblk * 8) = h;
}

__global__ void prep_w_kernel(const float* __restrict__ src, _Float16* __restrict__ dst) {
    int idx = blockIdx.x * 256 + threadIdx.x;
    const float* s = src + (size_t)idx * 8;
    floatx4 f0 = *(const floatx4*)s;
    floatx4 f1 = *(const floatx4*)(s + 4);
    half8 h;
#pragma unroll
    for (int e = 0; e < 4; ++e) { h[e] = (_Float16)f0[e]; h[4 + e] = (_Float16)f1[e]; }
    *(half8*)(dst + (size_t)idx * 8) = h;
}

__global__ __launch_bounds__(512, 2) void reservoir_kernel(
    const float* __restrict__ W0, const float* __restrict__ Win0,
    const float* __restrict__ W1, const float* __restrict__ Win1,
    const _Float16* __restrict__ XT, _Float16* __restrict__ S,
    unsigned int* __restrict__ FLG)
{
    const int wg = blockIdx.x;           // 0..7
    const int rsv = wg >> 2;             // reservoir 0/1
    const int chunk = wg & 3;            // 0..3 (128 cols each)
    const int wave = threadIdx.x >> 6;   // 0..7 (16 cols each)
    const int lane = threadIdx.x & 63;
    const int r15 = lane & 15;
    const int kg = (lane >> 4) << 3;     // 0,8,16,24
    const int nb = chunk * 128 + wave * 16;

    const float* Wm = rsv ? W1 : W0;
    const float* Wi = rsv ? Win1 : Win0;

    // --- static weight A-frags in VGPRs (f16) ---
    half8 wfrag[16];                     // K=512 -> 16 k-steps of 32
#pragma unroll
    for (int ks = 0; ks < 16; ++ks) {
        const float* p = Wm + (size_t)(nb + r15) * NR + ks * 32 + kg;
        floatx4 f0 = *(const floatx4*)p;
        floatx4 f1 = *(const floatx4*)(p + 4);
        half8 f;
#pragma unroll
        for (int e = 0; e < 4; ++e) { f[e] = (_Float16)f0[e]; f[4 + e] = (_Float16)f1[e]; }
        wfrag[ks] = f;
    }
    half8 ifrag[8];                      // K=256 -> 8 k-steps
#pragma unroll
    for (int ks = 0; ks < 8; ++ks) {
        const float* p = Wi + (size_t)(nb + r15) * DD + ks * 32 + kg;
        floatx4 f0 = *(const floatx4*)p;
        floatx4 f1 = *(const floatx4*)(p + 4);
        half8 f;
#pragma unroll
        for (int e = 0; e < 4; ++e) { f[e] = (_Float16)f0[e]; f[4 + e] = (_Float16)f1[e]; }
        ifrag[ks] = f;
    }

    floatx4 sprev = {0.f, 0.f, 0.f, 0.f};
    const int nst = nb + ((lane >> 4) << 2);   // 4 consecutive n per lane (D rows)

    for (int t = 0; t < TT; ++t) {
        // ---- input-drive frags: plain cached loads, issued before the poll ----
        const _Float16* xr = XT + ((size_t)t * BB + r15) * DD + kg;
        intx4 xi[8];
#pragma unroll
        for (int ks = 0; ks < 8; ++ks) xi[ks] = *(const intx4*)(xr + ks * 32);

        floatx4 acc[4];
#pragma unroll
        for (int j = 0; j < 4; ++j) acc[j] = (floatx4){0.f, 0.f, 0.f, 0.f};

        if (t > 0) {
            // ---- poll all 4 producer flags of this reservoir with one dwordx4 ----
            const unsigned int* fp = FLG + ((size_t)(t - 1) * 2 + rsv) * 4;
            intx4 f;
            do {
                asm volatile(
                    "global_load_dwordx4 %0, %1, off sc0 sc1\n\t"
                    "s_waitcnt vmcnt(0)"
                    : "=&v"(f) : "v"(fp) : "memory");
            } while (f[0] != t || f[1] != t || f[2] != t || f[3] != t);

            // ---- coherent state B-frag loads (bypass local L1/L2) ----
            const _Float16* sp = S + sidx(t - 1, rsv, r15, kg);
            intx4 bf[16];
            asm volatile(
                "global_load_dwordx4 %0, %16, off sc0 sc1\n\t"
                "global_load_dwordx4 %1, %16, off offset:64 sc0 sc1\n\t"
                "global_load_dwordx4 %2, %16, off offset:128 sc0 sc1\n\t"
                "global_load_dwordx4 %3, %16, off offset:192 sc0 sc1\n\t"
                "global_load_dwordx4 %4, %16, off offset:256 sc0 sc1\n\t"
                "global_load_dwordx4 %5, %16, off offset:320 sc0 sc1\n\t"
                "global_load_dwordx4 %6, %16, off offset:384 sc0 sc1\n\t"
                "global_load_dwordx4 %7, %16, off offset:448 sc0 sc1\n\t"
                "global_load_dwordx4 %8, %16, off offset:512 sc0 sc1\n\t"
                "global_load_dwordx4 %9, %16, off offset:576 sc0 sc1\n\t"
                "global_load_dwordx4 %10, %16, off offset:640 sc0 sc1\n\t"
                "global_load_dwordx4 %11, %16, off offset:704 sc0 sc1\n\t"
                "global_load_dwordx4 %12, %16, off offset:768 sc0 sc1\n\t"
                "global_load_dwordx4 %13, %16, off offset:832 sc0 sc1\n\t"
                "global_load_dwordx4 %14, %16, off offset:896 sc0 sc1\n\t"
                "global_load_dwordx4 %15, %16, off offset:960 sc0 sc1\n\t"
                "s_waitcnt vmcnt(0)"
                : "=&v"(bf[0]), "=&v"(bf[1]), "=&v"(bf[2]), "=&v"(bf[3]),
                  "=&v"(bf[4]), "=&v"(bf[5]), "=&v"(bf[6]), "=&v"(bf[7]),
                  "=&v"(bf[8]), "=&v"(bf[9]), "=&v"(bf[10]), "=&v"(bf[11]),
                  "=&v"(bf[12]), "=&v"(bf[13]), "=&v"(bf[14]), "=&v"(bf[15])
                : "v"(sp)
                : "memory");
            __builtin_amdgcn_sched_barrier(0);
#pragma unroll
            for (int ks = 0; ks < 16; ++ks) {
                half8 sf = __builtin_bit_cast(half8, bf[ks]);
                acc[ks & 3] = MFMA(wfrag[ks], sf, acc[ks & 3]);
            }
        }
#pragma unroll
        for (int ks = 0; ks < 8; ++ks) {
            half8 xf = __builtin_bit_cast(half8, xi[ks]);
            acc[ks & 3] = MFMA(ifrag[ks], xf, acc[ks & 3]);
        }

        floatx4 z = acc[0] + acc[1] + acc[2] + acc[3];
        floatx4 sn;
#pragma unroll
        for (int q = 0; q < 4; ++q)
            sn[q] = 0.7f * sprev[q] + 0.3f * tanh_fast(z[q]);
        sprev = sn;

        union { half4 h; unsigned long long u; } pk;
#pragma unroll
        for (int q = 0; q < 4; ++q) pk.h[q] = (_Float16)sn[q];
        const _Float16* spw = S + sidx(t, rsv, r15, nst);
        asm volatile("global_store_dwordx2 %0, %1, off sc0 sc1"
                     :: "v"(spw), "v"(pk.u) : "memory");

        // drain stores to the coherence point, join waves, publish flag
        asm volatile("s_waitcnt vmcnt(0)" ::: "memory");
        __syncthreads();
        if (threadIdx.x == 0) {
            const unsigned int* fw = FLG + ((size_t)t * 2 + rsv) * 4 + chunk;
            unsigned int v = (unsigned int)(t + 1);
            asm volatile("global_store_dword %0, %1, off sc0 sc1"
                         :: "v"(fw), "v"(v) : "memory");
        }
    }
}

__global__ __launch_bounds__(256) void gemm_h_kernel(
    const _Float16* __restrict__ S, const _Float16* __restrict__ W1F,
    const float* __restrict__ br1, _Float16* __restrict__ H)
{
    const int wave = threadIdx.x >> 6, lane = threadIdx.x & 63;
    const int r15 = lane & 15, kg = (lane >> 4) << 3;
    const int m0 = blockIdx.x * 64 + wave * 16;
    const int n0 = blockIdx.y * 64;
    // A row m = t*16 + b ; feature f = rsv*512 + k
    const int mr_ = m0 + r15;
    const int at = mr_ >> 4, ab = mr_ & 15;
    const _Float16* ap = S + ((((size_t)at * 2) * BB + ab) << 9) + kg;  // rsv0 base
    const _Float16* bp = W1F + (size_t)(n0 + r15) * HH + kg;
    floatx4 acc[4];
#pragma unroll
    for (int j = 0; j < 4; ++j) acc[j] = (floatx4){0.f, 0.f, 0.f, 0.f};
    for (int ks = 0; ks < HH / 32; ++ks) {
        size_t aoff = (size_t)((ks & 15) * 32) + (size_t)(ks >> 4) * (BB * NR); // rsv1 = +8192
        half8 af = __builtin_bit_cast(half8, *(const intx4*)(ap + aoff));
#pragma unroll
        for (int j = 0; j < 4; ++j) {
            half8 bf = __builtin_bit_cast(half8, *(const intx4*)(bp + (size_t)j * 16 * HH + ks * 32));
            acc[j] = MFMA(af, bf, acc[j]);
        }
    }
    const int mr = m0 + ((lane >> 4) << 2);
#pragma unroll
    for (int j = 0; j < 4; ++j) {
        int n = n0 + j * 16 + r15;
        float bb = br1[n];
#pragma unroll
        for (int q = 0; q < 4; ++q) {
            float h = acc[j][q] + bb;
            h = (h >= 0.f) ? h : 0.01f * h;
            H[(size_t)(mr + q) * HH + n] = (_Float16)h;
        }
    }
}

__global__ __launch_bounds__(256) void gemm_o_kernel(
    const _Float16* __restrict__ H, const _Float16* __restrict__ W2F,
    const float* __restrict__ br2, float* __restrict__ OUT)
{
    const int wave = threadIdx.x >> 6, lane = threadIdx.x & 63;
    const int r15 = lane & 15, kg = (lane >> 4) << 3;
    const int m0 = blockIdx.x * 64 + wave * 16;
    const int n0 = blockIdx.y * 64;
    const _Float16* ap = H + (size_t)(m0 + r15) * HH + kg;
    const _Float16* bp = W2F + (size_t)(n0 + r15) * HH + kg;
    floatx4 acc[4];
#pragma unroll
    for (int j = 0; j < 4; ++j) acc[j] = (floatx4){0.f, 0.f, 0.f, 0.f};
    for (int ks = 0; ks < HH / 32; ++ks) {
        half8 af = __builtin_bit_cast(half8, *(const intx4*)(ap + ks * 32));
#pragma unroll
        for (int j = 0; j < 4; ++j) {
            half8 bf = __builtin_bit_cast(half8, *(const intx4*)(bp + (size_t)j * 16 * HH + ks * 32));
            acc[j] = MFMA(af, bf, acc[j]);
        }
    }
    const int mr = m0 + ((lane >> 4) << 2);
#pragma unroll
    for (int j = 0; j < 4; ++j) {
        int n = n0 + j * 16 + r15;
        float bb = br2[n];
#pragma unroll
        for (int q = 0; q < 4; ++q) {
            int m = mr + q;           // m = t*16 + b
            int b = m & 15;
            int tt = m >> 4;
            OUT[(size_t)b * TT * EE + (size_t)tt * EE + n] = acc[j][q] + bb;
        }
    }
}

extern "C" void kernel_launch(void* const* d_in, const int* in_sizes, int n_in,
                              void* d_out, int out_size, void* d_ws, size_t ws_size,
                              hipStream_t stream) {
    const float* x    = (const float*)d_in[0];
    const float* W0   = (const float*)d_in[1];
    const float* Win0 = (const float*)d_in[2];
    const float* W1   = (const float*)d_in[3];
    const float* Win1 = (const float*)d_in[4];
    const float* Wr1  = (const float*)d_in[5];
    const float* br1  = (const float*)d_in[6];
    const float* Wr2  = (const float*)d_in[7];
    const float* br2  = (const float*)d_in[8];
    float* out = (float*)d_out;

    char* ws = (char*)d_ws;
    _Float16* XT  = (_Float16*)(ws + OFF_XT);
    _Float16* S   = (_Float16*)(ws + OFF_S);
    _Float16* H   = (_Float16*)(ws + OFF_H);
    _Float16* W1F = (_Float16*)(ws + OFF_W1F);
    _Float16* W2F = (_Float16*)(ws + OFF_W2F);
    unsigned int* FLG = (unsigned int*)(ws + OFF_FLG);

    zero_flags_kernel<<<64, 256, 0, stream>>>(FLG);
    prep_x_kernel<<<4096, 256, 0, stream>>>(x, XT);
    prep_w_kernel<<<512, 256, 0, stream>>>(Wr1, W1F);
    prep_w_kernel<<<128, 256, 0, stream>>>(Wr2, W2F);
    reservoir_kernel<<<8, 512, 0, stream>>>(W0, Win0, W1, Win1, XT, S, FLG);
    gemm_h_kernel<<<dim3(512, 16), 256, 0, stream>>>(S, W1F, br1, H);
    gemm_o_kernel<<<dim3(512, 4), 256, 0, stream>>>(H, W2F, br2, out);
}